// Round 8
// baseline (1054.084 us; speedup 1.0000x reference)
//
#include <hip/hip_runtime.h>
#include <cstdint>
#include <cstddef>

#define HW 4096
#define NPQ 3844

typedef __attribute__((ext_vector_type(8))) short bf16x8;
typedef __attribute__((ext_vector_type(4))) float f32x4;
typedef unsigned short ushort;
typedef unsigned int uint;

__device__ __forceinline__ ushort f2bu(float f){
  uint u = __float_as_uint(f);
  uint r = (u + 0x7fffu + ((u >> 16) & 1u)) >> 16;
  return (ushort)r;
}
__device__ __forceinline__ uint umax2x16(uint a, uint b){
  uint ah = a >> 16, bh = b >> 16, al = a & 0xffffu, bl = b & 0xffffu;
  uint h = ah > bh ? ah : bh, l = al > bl ? al : bl;
  return (h << 16) | l;
}

// HBM->LDS DMA, 16B per lane. LDS dest must be wave-uniform base; HW adds lane*16.
__device__ __forceinline__ void gll16(const float* g, float* l){
  __builtin_amdgcn_global_load_lds(
      (const __attribute__((address_space(1))) void*)g,
      (__attribute__((address_space(3))) void*)l, 16, 0, 0);
}

// ---------------- feature matching ----------------

// per-pixel channel L2 normalize; block = 16 px x 16 channel-groups, LDS tree reduce.
// blockIdx.y selects feature (f1/f2), blockIdx.z selects batch (strided).
// 16 per-thread values cached in registers across the two passes.
__global__ __launch_bounds__(256) void k_norm2(const float* __restrict__ fA,
                                               const float* __restrict__ fB,
                                               float* __restrict__ fnA,
                                               float* __restrict__ fnB,
                                               float* __restrict__ spixA,
                                               float* __restrict__ spixB,
                                               size_t inStride, size_t outStride,
                                               int sStride){
  const size_t zb = blockIdx.z;
  const float* f  = (blockIdx.y ? fB  : fA) + zb*inStride;
  float* fn       = (blockIdx.y ? fnB : fnA) + zb*outStride;
  float* spix     = (blockIdx.y ? spixB : spixA) + zb*(size_t)sStride;
  __shared__ float red[16][17];
  const int px = threadIdx.x & 15, cg = threadIdx.x >> 4;
  const int pix = blockIdx.x*16 + px;
  float v[16];
  float s = 0.f;
  #pragma unroll
  for (int i=0;i<16;i++){ v[i] = f[(cg*16+i)*HW + pix]; s += v[i]*v[i]; }
  red[cg][px] = s; __syncthreads();
  for (int off=8; off>0; off>>=1){
    if (cg < off) red[cg][px] += red[cg+off][px];
    __syncthreads();
  }
  float n = fmaxf(sqrtf(red[0][px]), 1e-12f);
  float s2 = 0.f;
  #pragma unroll
  for (int i=0;i<16;i++){
    float w = v[i] / n;   // keep fdiv (matches reference rounding)
    fn[(cg*16+i)*HW + pix] = w;
    s2 += w*w;
  }
  __syncthreads();
  red[cg][px] = s2; __syncthreads();
  for (int off=8; off>0; off>>=1){
    if (cg < off) red[cg][px] += red[cg+off][px];
    __syncthreads();
  }
  if (cg == 0) spix[pix] = red[0][px];
}

__global__ __launch_bounds__(256) void k_normpq(const float* __restrict__ s1,
                                                const float* __restrict__ s2,
                                                float* __restrict__ normP,
                                                float* __restrict__ normQ,
                                                int sStride, int nStride){
  int p = blockIdx.x*256 + threadIdx.x;
  if (p >= NPQ) return;
  const size_t zb = blockIdx.z;
  s1 += zb*(size_t)sStride; s2 += zb*(size_t)sStride;
  normP += zb*(size_t)nStride; normQ += zb*(size_t)nStride;
  int py = p/62, px = p - py*62;
  float a=0.f, b=0.f;
  for (int dy=0;dy<3;dy++)
    for (int dx=0;dx<3;dx++){
      int o = (py+dy)*64 + px+dx;
      a += s1[o]; b += s2[o];
    }
  normP[p] = sqrtf(a) + 1e-5f;
  normQ[p] = sqrtf(b) + 1e-5f;
}

// E[m][n] = sum_k A[k][m]*B[k][n]; per-element fmaf chain k=0..255 ascending
// (bit-identical to rounds 3/5). 128m x 256n tile, 8x16 acc/thread, 256 threads.
// Round 13: BK 16->8. LDS 48KB->24KB removes the residency cap (measured 21%
// occupancy ~= 2 blocks/CU at 48KB despite a theoretical 3): now 4 blocks/CU
// (VGPR-capped). 32 K-tiles x 1 barrier; 3 DMA loads/tile (1 A + 2 B), same
// flat 16B/lane maps. Compute per tile (2048 VALU cyc) still >> HBM latency,
// so the end-of-tile drain stays cheap. k ascending across tiles -> E bit-identical.
__global__ __launch_bounds__(256) void k_gemm(const float* __restrict__ A,
                                              const float* __restrict__ B,
                                              float* __restrict__ E,
                                              size_t abStride, size_t eStride){
  __shared__ __align__(16) float As[2][8][128];
  __shared__ __align__(16) float Bs[2][8][256];
  const size_t zb = blockIdx.z;
  A += zb*abStride; B += zb*abStride; E += zb*eStride;
  const int m0 = blockIdx.y*128, n0 = blockIdx.x*256;
  const int tid = threadIdx.x;
  const int ty = tid>>4, tx = tid&15;
  const int wave = tid>>6;              // uniform within wave

  // staging maps (flat float index = chunk*1024 + tid*4):
  //  A-tile 8x128 (1024 f): row = tid>>5 (0..7), col = (tid&31)*4   [1 chunk]
  //  B-tile 8x256 (2048 f): row = tid>>6 (+4 chunk 1), col = (tid&63)*4
  const int arow = tid>>5;
  const int acol = (tid&31)*4;
  const int brow = tid>>6;
  const int bcol = (tid&63)*4;
  const float* Ag = A + (size_t)arow*HW + m0 + acol;
  const float* Bg = B + (size_t)brow*HW + n0 + bcol;

  float acc[8][16];
  #pragma unroll
  for (int i=0;i<8;i++)
    #pragma unroll
    for (int j=0;j<16;j++) acc[i][j]=0.f;

  {
    float* ad = &As[0][0][0] + wave*256;
    float* bd = &Bs[0][0][0] + wave*256;
    gll16(Ag,                 ad);
    gll16(Bg,                 bd);
    gll16(Bg + (size_t)4*HW,  bd + 1024);
  }
  __syncthreads();   // drains vmcnt: tile-0 DMA landed

  for (int t=0;t<32;t++){
    const int cur = t&1;
    if (t < 31){
      const float* An = Ag + (size_t)(t+1)*8*HW;
      const float* Bn = Bg + (size_t)(t+1)*8*HW;
      float* ad = &As[cur^1][0][0] + wave*256;
      float* bd = &Bs[cur^1][0][0] + wave*256;
      gll16(An,                 ad);
      gll16(Bn,                 bd);
      gll16(Bn + (size_t)4*HW,  bd + 1024);
    }
    #pragma unroll
    for (int k=0;k<8;k++){
      float4 a0 = *(const float4*)&As[cur][k][ty*8];
      float4 a1 = *(const float4*)&As[cur][k][ty*8+4];
      float4 b0 = *(const float4*)&Bs[cur][k][tx*4];
      float4 b1 = *(const float4*)&Bs[cur][k][64+tx*4];
      float4 b2 = *(const float4*)&Bs[cur][k][128+tx*4];
      float4 b3 = *(const float4*)&Bs[cur][k][192+tx*4];
#define GEMM_ROW(i, AV)                                   \
      acc[i][0]  = fmaf(AV, b0.x, acc[i][0]);             \
      acc[i][1]  = fmaf(AV, b0.y, acc[i][1]);             \
      acc[i][2]  = fmaf(AV, b0.z, acc[i][2]);             \
      acc[i][3]  = fmaf(AV, b0.w, acc[i][3]);             \
      acc[i][4]  = fmaf(AV, b1.x, acc[i][4]);             \
      acc[i][5]  = fmaf(AV, b1.y, acc[i][5]);             \
      acc[i][6]  = fmaf(AV, b1.z, acc[i][6]);             \
      acc[i][7]  = fmaf(AV, b1.w, acc[i][7]);             \
      acc[i][8]  = fmaf(AV, b2.x, acc[i][8]);             \
      acc[i][9]  = fmaf(AV, b2.y, acc[i][9]);             \
      acc[i][10] = fmaf(AV, b2.z, acc[i][10]);            \
      acc[i][11] = fmaf(AV, b2.w, acc[i][11]);            \
      acc[i][12] = fmaf(AV, b3.x, acc[i][12]);            \
      acc[i][13] = fmaf(AV, b3.y, acc[i][13]);            \
      acc[i][14] = fmaf(AV, b3.z, acc[i][14]);            \
      acc[i][15] = fmaf(AV, b3.w, acc[i][15]);
      GEMM_ROW(0, a0.x)
      GEMM_ROW(1, a0.y)
      GEMM_ROW(2, a0.z)
      GEMM_ROW(3, a0.w)
      GEMM_ROW(4, a1.x)
      GEMM_ROW(5, a1.y)
      GEMM_ROW(6, a1.z)
      GEMM_ROW(7, a1.w)
#undef GEMM_ROW
    }
    __syncthreads();  // drains vmcnt (tile t+1 DMA) + all waves done reading buf cur
  }

  #pragma unroll
  for (int i=0;i<8;i++){
    float* rowp = E + (size_t)(m0+ty*8+i)*HW + n0;
    *(float4*)(rowp + tx*4)       = make_float4(acc[i][0], acc[i][1], acc[i][2], acc[i][3]);
    *(float4*)(rowp + 64 + tx*4)  = make_float4(acc[i][4], acc[i][5], acc[i][6], acc[i][7]);
    *(float4*)(rowp + 128 + tx*4) = make_float4(acc[i][8], acc[i][9], acc[i][10], acc[i][11]);
    *(float4*)(rowp + 192 + tx*4) = make_float4(acc[i][12], acc[i][13], acc[i][14], acc[i][15]);
  }
}

// per patch P: max/argmax over Q (round-5 arithmetic; blockIdx.y = batch).
// Bijective XCD swizzle of the patch index for per-XCD L2 reuse of E row-bands.
__global__ __launch_bounds__(256) void k_reduce(const float* __restrict__ E,
                                                const float* __restrict__ normP,
                                                const float* __restrict__ normQ,
                                                float* __restrict__ maxval,
                                                int* __restrict__ maxidx,
                                                size_t eStride, int nStride){
  // m204 bijective swizzle: NPQ = 3844 = 8*480 + 4
  const int orig = blockIdx.x;
  const int xcd = orig & 7, ii = orig >> 3;
  const int qc = NPQ >> 3, rc = NPQ & 7;   // 480, 4
  const int p = (xcd < rc) ? xcd*(qc+1) + ii : rc*(qc+1) + (xcd-rc)*qc + ii;

  const int bz = blockIdx.y;
  E += (size_t)bz*eStride;
  normP += (size_t)bz*(size_t)nStride;
  normQ += (size_t)bz*(size_t)nStride;
  const int py = p/62, px = p - py*62;
  const int t = threadIdx.x;
  float best = -3.0e38f; int bq = 1<<30;

  if (t < 248){
    const int qy = t >> 2, g = t & 3;
    const int qx0 = g*16;
    const int cnt = (g==3) ? 14 : 16;
    float s[16];
    #pragma unroll
    for (int j=0;j<16;j++) s[j]=0.f;
    #pragma unroll
    for (int dy=0;dy<3;dy++){
      const int cbase = (qy+dy)*64 + qx0;
      #pragma unroll
      for (int dx=0;dx<3;dx++){
        const float* row = E + (size_t)((py+dy)*64 + px+dx)*HW + cbase;
        float4 w0 = *(const float4*)(row);
        float4 w1 = *(const float4*)(row+4);
        float4 w2 = *(const float4*)(row+8);
        float4 w3 = *(const float4*)(row+12);
        float4 w4 = (g<3) ? *(const float4*)(row+16) : make_float4(0.f,0.f,0.f,0.f);
        float w[20] = {w0.x,w0.y,w0.z,w0.w, w1.x,w1.y,w1.z,w1.w,
                       w2.x,w2.y,w2.z,w2.w, w3.x,w3.y,w3.z,w3.w,
                       w4.x,w4.y,w4.z,w4.w};
        #pragma unroll
        for (int j=0;j<16;j++) s[j] += w[dx+j];
      }
    }
    const int qbase = qy*62 + qx0;
    for (int j=0;j<cnt;j++){
      float v = s[j] / normQ[qbase + j];
      if (v > best){ best = v; bq = qbase + j; }
    }
  }

  __shared__ float sv[256];
  __shared__ int si[256];
  sv[t] = best; si[t] = bq;
  __syncthreads();
  for (int off=128; off>0; off>>=1){
    if (t < off){
      float ov = sv[t+off]; int oi = si[t+off];
      float cv = sv[t];     int ci = si[t];
      if (ov > cv || (ov == cv && oi < ci)){ sv[t]=ov; si[t]=oi; }
    }
    __syncthreads();
  }
  if (t == 0){
    maxval[bz*NPQ + p] = sv[0] / normP[p];
    maxidx[bz*NPQ + p] = si[0];
  }
}

// ---------------- flow / sim outputs (unchanged) ----------------

__global__ __launch_bounds__(256) void k_flow3(const int* __restrict__ maxidx,
                                               const float* __restrict__ maxval,
                                               float* __restrict__ flow3ws,
                                               float* __restrict__ sim3ws,
                                               float* __restrict__ oflow,
                                               float* __restrict__ osim){
  int idx = blockIdx.x*256 + threadIdx.x;
  if (idx >= 4*HW) return;
  int b = idx >> 12, r = idx & 4095;
  int y = r >> 6, x = r & 63;
  float fx = 0.f, fy = 0.f;
  if (y < 62 && x < 62){
    int mi = maxidx[b*NPQ + y*62 + x];
    int qy = mi/62, qx = mi - qy*62;
    fx = (float)(qx - x);
    fy = (float)(qy - y);
  }
  flow3ws[idx*2] = fx; flow3ws[idx*2+1] = fy;
  oflow[idx*2] = fx; oflow[idx*2+1] = fy;
  float sv = 0.f;
  if (y >= 1 && y <= 62 && x >= 1 && x <= 62)
    sv = maxval[b*NPQ + (y-1)*62 + (x-1)];
  sim3ws[idx] = sv;
  osim[idx] = sv;
}

__global__ __launch_bounds__(256) void k_off3(const float* __restrict__ flow3ws,
                                              float* __restrict__ out){
  int idx = blockIdx.x*256 + threadIdx.x;
  if (idx >= 4*9*HW) return;
  int b = idx / (9*HW);
  int rem = idx - b*9*HW;
  int k = rem >> 12;
  int r = rem & 4095;
  int y = r >> 6, x = r & 63;
  int i = k/3, j = k - i*3;
  float fx = 0.f, fy = 0.f;
  if (y >= i && x >= j){
    int s = (b*HW + (y-i)*64 + (x-j))*2;
    fx = flow3ws[s]; fy = flow3ws[s+1];
  }
  out[idx*2] = fx; out[idx*2+1] = fy;
}

__global__ __launch_bounds__(256) void k_flowS(const float* __restrict__ flow3ws,
                                               const float* __restrict__ sim3ws,
                                               float* __restrict__ oflow,
                                               float* __restrict__ osim,
                                               int S, int N){
  int idx = blockIdx.x*256 + threadIdx.x;
  int tot = 4*N*N;
  if (idx >= tot) return;
  int b = idx/(N*N);
  int r = idx - b*N*N;
  int y = r/N, x = r - y*N;
  int s = b*HW + (y/S)*64 + (x/S);
  float fx = flow3ws[s*2] * (float)S;
  float fy = flow3ws[s*2+1] * (float)S;
  oflow[idx*2] = fx; oflow[idx*2+1] = fy;
  osim[idx] = sim3ws[s];
}

__global__ __launch_bounds__(256) void k_offS(const float* __restrict__ flow3ws,
                                              float* __restrict__ out,
                                              int S, int N){
  int idx = blockIdx.x*256 + threadIdx.x;
  int tot = 4*9*N*N;
  if (idx >= tot) return;
  int b = idx/(9*N*N);
  int rem = idx - b*9*N*N;
  int k = rem/(N*N);
  int r = rem - k*(N*N);
  int y = r/N, x = r - y*N;
  int i = k/3, j = k - i*3;
  float fx = 0.f, fy = 0.f;
  int sy = y - S*i, sx = x - S*j;
  if (sy >= 0 && sx >= 0){
    int s = (b*HW + (sy/S)*64 + (sx/S))*2;
    fx = flow3ws[s] * (float)S;
    fy = flow3ws[s+1] * (float)S;
  }
  out[idx*2] = fx; out[idx*2+1] = fy;
}

// ---------------- VGG ----------------

// weight transform: fp32 OIHW -> bf16 [tap][oc][ci]
__global__ __launch_bounds__(256) void k_wt(const float* __restrict__ w,
                                            ushort* __restrict__ wt,
                                            int Cout, int Cin){
  int idx = blockIdx.x*256 + threadIdx.x;
  int tot = Cout*Cin*9;
  if (idx >= tot) return;
  int o = idx / (Cin*9);
  int rem = idx - o*(Cin*9);
  int i = rem / 9;
  int tap = rem - i*9;
  wt[((size_t)tap*Cout + o)*Cin + i] = f2bu(w[idx]);
}

// conv1_1: direct fp32, Cin=3, H=W=256, fused imagenet normalize; batched via z
// (z: b = z>>3, oc-group = z&7). Writes fp32 CHW (d_out) + bf16 HWC (next stage).
__global__ __launch_bounds__(256) void k_conv1(const float* __restrict__ img,
                                               const float* __restrict__ w,
                                               const float* __restrict__ bias,
                                               float* __restrict__ outf,
                                               ushort* __restrict__ outb){
  __shared__ float sIn[3][18][20];
  __shared__ float sW[8][3][9];
  const int tx = threadIdx.x & 15, ty = threadIdx.x >> 4;
  const int x0 = blockIdx.x*16, y0 = blockIdx.y*16;
  const int b = blockIdx.z >> 3;
  const int oc0 = (blockIdx.z & 7)*8;
  const float MEAN[3] = {0.485f,0.456f,0.406f};
  const float STDV[3] = {0.229f,0.224f,0.225f};
  const float* in = img + (size_t)b*3*65536;
  for (int i = threadIdx.x; i < 3*324; i += 256){
    int ci = i / 324;
    int rr = i - ci*324;
    int iy = rr / 18, ix = rr - iy*18;
    int gy = y0 + iy - 1, gx = x0 + ix - 1;
    float v = 0.f;
    if (gy >= 0 && gy < 256 && gx >= 0 && gx < 256)
      v = (in[ci*65536 + gy*256 + gx] - MEAN[ci]) / STDV[ci];
    sIn[ci][iy][ix] = v;
  }
  if (threadIdx.x < 216){
    int o = threadIdx.x / 27;
    int rr = threadIdx.x - o*27;
    int ci = rr / 9, t = rr - ci*9;
    sW[o][ci][t] = w[((oc0+o)*3 + ci)*9 + t];
  }
  __syncthreads();
  float acc[8] = {0.f,0.f,0.f,0.f,0.f,0.f,0.f,0.f};
  for (int ci=0; ci<3; ci++){
    #pragma unroll
    for (int ky=0;ky<3;ky++){
      #pragma unroll
      for (int kx=0;kx<3;kx++){
        float v = sIn[ci][ty+ky][tx+kx];
        #pragma unroll
        for (int o=0;o<8;o++)
          acc[o] = fmaf(v, sW[o][ci][ky*3+kx], acc[o]);
      }
    }
  }
  #pragma unroll
  for (int o=0;o<8;o++){
    float r = fmaxf(acc[o] + bias[oc0+o], 0.f);
    outf[(size_t)b*4194304 + (size_t)(oc0+o)*65536 + (size_t)(y0+ty)*256 + (x0+tx)] = r;
    outb[(size_t)b*4194304 + ((size_t)(y0+ty)*256 + (x0+tx))*64 + (oc0+o)] = f2bu(r);
  }
}

// MFMA implicit-GEMM 3x3 SAME conv, bf16 in / fp32 acc; batched via z
// (z = b*zDiv + oc-tile; per-batch pointer strides in elements).
// A-fragments (weights) read directly from global (L2-hot, shared by all blocks);
// LDS holds only sX; one barrier per block.
__global__ __launch_bounds__(256) void k_conv_mfma(const ushort* __restrict__ X,
                                                   const ushort* __restrict__ Wt,
                                                   const float* __restrict__ bias,
                                                   ushort* __restrict__ outHWC,
                                                   float* __restrict__ outCHW,
                                                   int Cin, int Cout, int H, int W,
                                                   int zDiv, size_t xStride,
                                                   size_t hwcStride, size_t chwStride){
  extern __shared__ ushort smem[];
  const int CS = Cin + 8;
  ushort* sX = smem;                      // [10][18][CS]
  const int tid = threadIdx.x;
  const int wave = tid >> 6, lane = tid & 63;
  const int quad = lane >> 4, l16 = lane & 15;
  const int bz = blockIdx.z / zDiv;
  const int zo = blockIdx.z - bz*zDiv;
  const int x0 = blockIdx.x * 16, y0 = blockIdx.y * 8, oc0 = zo * 64;
  X += (size_t)bz * xStride;
  if (outHWC) outHWC += (size_t)bz * hwcStride;
  if (outCHW) outCHW += (size_t)bz * chwStride;
  const int nci8 = Cin >> 3;
  const int c8s = (Cin == 128) ? 4 : 3;
  const int c8m = nci8 - 1;

  for (int i = tid; i < 180*nci8; i += 256){
    int c8 = i & c8m;
    int rest = i >> c8s;
    int px = rest % 18;
    int row = rest / 18;
    int gy = y0 - 1 + row, gx = x0 - 1 + px;
    uint4 v = make_uint4(0u,0u,0u,0u);
    if (gy >= 0 && gy < H && gx >= 0 && gx < W)
      v = *(const uint4*)(X + ((size_t)gy*W + gx)*Cin + c8*8);
    *(uint4*)(sX + (row*18 + px)*CS + c8*8) = v;
  }
  __syncthreads();

  f32x4 acc[2][4];
  #pragma unroll
  for (int m=0;m<2;m++)
    #pragma unroll
    for (int r=0;r<4;r++) acc[m][r] = (f32x4){0.f,0.f,0.f,0.f};

  const int my = (wave>>1)*4;
  const int mo = (wave&1)*32;

  for (int tap = 0; tap < 9; tap++){
    int dy = tap/3 - 1, dx = tap - (tap/3)*3 - 1;
    const ushort* wsrc = Wt + ((size_t)tap*Cout + oc0)*Cin;
    for (int k0 = 0; k0 < Cin; k0 += 32){
      bf16x8 A0 = *(const bf16x8*)(wsrc + (mo + l16)*Cin + k0 + quad*8);
      bf16x8 A1 = *(const bf16x8*)(wsrc + (mo + 16 + l16)*Cin + k0 + quad*8);
      #pragma unroll
      for (int r = 0; r < 4; r++){
        bf16x8 B = *(const bf16x8*)(sX + ((1 + my + r + dy)*18 + (1 + l16 + dx))*CS + k0 + quad*8);
        acc[0][r] = __builtin_amdgcn_mfma_f32_16x16x32_bf16(A0, B, acc[0][r], 0, 0, 0);
        acc[1][r] = __builtin_amdgcn_mfma_f32_16x16x32_bf16(A1, B, acc[1][r], 0, 0, 0);
      }
    }
  }

  const int x = x0 + l16;
  #pragma unroll
  for (int m = 0; m < 2; m++){
    int ocb = oc0 + mo + m*16 + quad*4;
    float4 bv = *(const float4*)(bias + ocb);
    #pragma unroll
    for (int r = 0; r < 4; r++){
      int y = y0 + my + r;
      float v0 = fmaxf(acc[m][r][0] + bv.x, 0.f);
      float v1 = fmaxf(acc[m][r][1] + bv.y, 0.f);
      float v2 = fmaxf(acc[m][r][2] + bv.z, 0.f);
      float v3 = fmaxf(acc[m][r][3] + bv.w, 0.f);
      if (outHWC){
        uint lo = (uint)f2bu(v0) | ((uint)f2bu(v1) << 16);
        uint hi = (uint)f2bu(v2) | ((uint)f2bu(v3) << 16);
        // GLOBAL oc index (round-4 bug: localizing collided z-tiles)
        uint2* dst = (uint2*)(outHWC + ((size_t)y*W + x)*Cout + ocb);
        *dst = make_uint2(lo, hi);
      }
      if (outCHW){
        size_t base = (size_t)ocb*H*W + (size_t)y*W + x;
        outCHW[base]                 = v0;
        outCHW[base +   (size_t)H*W] = v1;
        outCHW[base + 2*(size_t)H*W] = v2;
        outCHW[base + 3*(size_t)H*W] = v3;
      }
    }
  }
}

// 2x2 max-pool on HWC bf16 (post-relu, non-negative -> u16 compare); batched via z
__global__ __launch_bounds__(256) void k_pool_h(const ushort* __restrict__ in,
                                                ushort* __restrict__ out,
                                                int C, int Wo, int s,
                                                size_t inStride, size_t outStride){
  in  += (size_t)blockIdx.z * inStride;
  out += (size_t)blockIdx.z * outStride;
  int idx = blockIdx.x*256 + threadIdx.x;
  int nc8 = C >> 3;
  if (idx >= Wo*nc8) return;
  int x = idx >> s;
  int c8 = idx & (nc8 - 1);
  int y = blockIdx.y;
  int Wi = 2*Wo;
  const ushort* p = in + ((size_t)(2*y)*Wi + 2*x)*C + c8*8;
  uint4 a = *(const uint4*)p;
  uint4 b = *(const uint4*)(p + C);
  uint4 c = *(const uint4*)(p + (size_t)Wi*C);
  uint4 d = *(const uint4*)(p + (size_t)Wi*C + C);
  uint4 m;
  m.x = umax2x16(umax2x16(a.x,b.x), umax2x16(c.x,d.x));
  m.y = umax2x16(umax2x16(a.y,b.y), umax2x16(c.y,d.y));
  m.z = umax2x16(umax2x16(a.z,b.z), umax2x16(c.z,d.z));
  m.w = umax2x16(umax2x16(a.w,b.w), umax2x16(c.w,d.w));
  *(uint4*)(out + ((size_t)y*Wo + x)*C + c8*8) = m;
}

// ---------------- launch ----------------

extern "C" void kernel_launch(void* const* d_in, const int* in_sizes, int n_in,
                              void* d_out, int out_size, void* d_ws, size_t ws_size,
                              hipStream_t stream){
  const float* f1  = (const float*)d_in[0];
  const float* f2  = (const float*)d_in[1];
  const float* img = (const float*)d_in[2];
  const float* w11 = (const float*)d_in[3];  const float* b11 = (const float*)d_in[4];
  const float* w12 = (const float*)d_in[5];  const float* b12 = (const float*)d_in[6];
  const float* w21 = (const float*)d_in[7];  const float* b21 = (const float*)d_in[8];
  const float* w22 = (const float*)d_in[9];  const float* b22 = (const float*)d_in[10];
  const float* w31 = (const float*)d_in[11]; const float* b31 = (const float*)d_in[12];
  float* out = (float*)d_out;

  float* F = (float*)d_ws;
  float* E = F;                         // batch-0 E (64 MB); VGG reuses this region

  // VGG weight buffers (dead region after matching in both layouts)
  ushort* wt1  = (ushort*)(F + 16777216);
  ushort* wt2a = (ushort*)(F + 16795648);
  ushort* wt2b = (ushort*)(F + 16832512);
  ushort* wt3  = (ushort*)(F + 16906240);

  // VGG activations alias the E region (64 MB), all 4 batches concurrently.
  ushort* EU  = (ushort*)E;
  ushort* t1a = EU;                 // 4 x 4,194,304
  ushort* t2a = EU + 16777216;      // 4 x 4,194,304
  ushort* p1a = EU;                 // 4 x 1,048,576  (t1 dead)
  ushort* t3a = EU + 4194304;       // 4 x 2,097,152
  ushort* t4a = EU + 16777216;      // 4 x 2,097,152  (t2 dead)
  ushort* p2a = EU;                 // 4 x   524,288  (p1 dead)

  const size_t O_OFF3 = 0, O_OFF2 = 294912, O_OFF1 = 1474560;
  const size_t O_FLOW3 = 6193152, O_FLOW2 = 6225920, O_FLOW1 = 6356992;
  const size_t O_SIM3 = 6881280, O_SIM2 = 6897664, O_SIM1 = 6963200;
  const size_t O_R1 = 7225344, O_R2 = 24002560, O_R3 = 32391168;

  // Big-workspace layout: 4x E (256 MB) + staging past it. ~302.6 MB total.
  const bool big = ws_size >= 302600000ull;

  float *mval, *fl3, *sm3; int* midx;

  if (big){
    float* f1n = F + 67108864;   // 4 x 1,048,576
    float* f2n = F + 71303168;   // 4 x 1,048,576
    float* s1  = F + 75497472;   // 4 x 4096
    float* s2  = F + 75513856;
    float* nP  = F + 75530240;   // 4 x 4096
    float* nQ  = F + 75546624;
    mval = F + 75563008;         // 4 x 4096
    midx = (int*)(F + 75579392);
    fl3  = F + 75595776;         // 4 x 4096 x 2
    sm3  = F + 75628544;         // 4 x 4096

    // fully batched matching: one launch per stage, grid.z = batch
    k_norm2<<<dim3(256,2,4),256,0,stream>>>(f1, f2, f1n, f2n, s1, s2,
                                            (size_t)256*HW, 1048576, 4096);
    k_normpq<<<dim3(16,1,4),256,0,stream>>>(s1, s2, nP, nQ, 4096, 4096);
    k_gemm<<<dim3(16,32,4),256,0,stream>>>(f1n, f2n, E, 1048576, 16777216);
    k_reduce<<<dim3(NPQ,4),256,0,stream>>>(E, nP, nQ, mval, midx, 16777216, 4096);
  } else {
    // fallback: serial layout (E reused per batch)
    float* f1n  = F + 16777216;
    float* f2n  = F + 17825792;
    float* s1   = F + 18874368;
    float* s2   = F + 18878464;
    float* nP   = F + 18882560;
    float* nQ   = F + 18886656;
    mval = F + 18890752;
    midx = (int*)(F + 18907136);
    fl3  = F + 18923520;
    sm3  = F + 18956288;

    for (int b=0;b<4;b++){
      const float* f1b  = f1 + (size_t)b*256*HW;
      const float* f2b2 = f2 + (size_t)b*256*HW;
      k_norm2<<<dim3(256,2,1),256,0,stream>>>(f1b, f2b2, f1n, f2n, s1, s2, 0, 0, 0);
      k_normpq<<<dim3(16,1,1),256,0,stream>>>(s1, s2, nP, nQ, 0, 0);
      k_gemm<<<dim3(16,32,1),256,0,stream>>>(f1n, f2n, E, 0, 0);
      k_reduce<<<dim3(NPQ,1),256,0,stream>>>(E, nP, nQ, mval + b*NPQ, midx + b*NPQ, 0, 0);
    }
  }

  k_flow3<<<64,256,0,stream>>>(midx, mval, fl3, sm3, out+O_FLOW3, out+O_SIM3);
  k_off3<<<576,256,0,stream>>>(fl3, out+O_OFF3);
  k_flowS<<<256,256,0,stream>>>(fl3, sm3, out+O_FLOW2, out+O_SIM2, 2, 128);
  k_offS<<<2304,256,0,stream>>>(fl3, out+O_OFF2, 2, 128);
  k_flowS<<<1024,256,0,stream>>>(fl3, sm3, out+O_FLOW1, out+O_SIM1, 4, 256);
  k_offS<<<9216,256,0,stream>>>(fl3, out+O_OFF1, 4, 256);

  k_wt<<<144,256,0,stream>>>(w12, wt1, 64, 64);
  k_wt<<<288,256,0,stream>>>(w21, wt2a, 128, 64);
  k_wt<<<576,256,0,stream>>>(w22, wt2b, 128, 128);
  k_wt<<<1152,256,0,stream>>>(w31, wt3, 256, 128);

  const int smem64  = 180*72*2;    // sX only
  const int smem128 = 180*136*2;

  // batched VGG (grid.z carries batch)
  k_conv1<<<dim3(16,16,32),256,0,stream>>>(img, w11, b11, out + O_R1, t1a);
  k_conv_mfma<<<dim3(16,32,4),256,smem64,stream>>>(t1a, wt1, b12, t2a, nullptr,
      64, 64, 256, 256, 1, 4194304, 4194304, 0);
  k_pool_h<<<dim3(4,128,4),256,0,stream>>>(t2a, p1a, 64, 128, 3, 4194304, 1048576);
  k_conv_mfma<<<dim3(8,16,8),256,smem64,stream>>>(p1a, wt2a, b21, t3a, out + O_R2,
      64, 128, 128, 128, 2, 1048576, 2097152, 2097152);
  k_conv_mfma<<<dim3(8,16,8),256,smem128,stream>>>(t3a, wt2b, b22, t4a, nullptr,
      128, 128, 128, 128, 2, 2097152, 2097152, 0);
  k_pool_h<<<dim3(4,64,4),256,0,stream>>>(t4a, p2a, 128, 64, 4, 2097152, 524288);
  k_conv_mfma<<<dim3(4,8,16),256,smem128,stream>>>(p2a, wt3, b31, nullptr, out + O_R3,
      128, 256, 64, 64, 4, 524288, 0, 1048576);
}

// Round 9
// 1017.413 us; speedup vs baseline: 1.0360x; 1.0360x over previous
//
#include <hip/hip_runtime.h>
#include <cstdint>
#include <cstddef>

#define HW 4096
#define NPQ 3844

#define O_OFF3 0
#define O_OFF2 294912
#define O_OFF1 1474560
#define O_FLOW3 6193152
#define O_FLOW2 6225920
#define O_FLOW1 6356992
#define O_SIM3 6881280
#define O_SIM2 6897664
#define O_SIM1 6963200
#define O_R1 7225344
#define O_R2 24002560
#define O_R3 32391168

typedef __attribute__((ext_vector_type(8))) short bf16x8;
typedef __attribute__((ext_vector_type(4))) float f32x4;
typedef unsigned short ushort;
typedef unsigned int uint;

__device__ __forceinline__ ushort f2bu(float f){
  uint u = __float_as_uint(f);
  uint r = (u + 0x7fffu + ((u >> 16) & 1u)) >> 16;
  return (ushort)r;
}
__device__ __forceinline__ uint umax2x16(uint a, uint b){
  uint ah = a >> 16, bh = b >> 16, al = a & 0xffffu, bl = b & 0xffffu;
  uint h = ah > bh ? ah : bh, l = al > bl ? al : bl;
  return (h << 16) | l;
}

// HBM->LDS DMA, 16B per lane. LDS dest must be wave-uniform base; HW adds lane*16.
__device__ __forceinline__ void gll16(const float* g, float* l){
  __builtin_amdgcn_global_load_lds(
      (const __attribute__((address_space(1))) void*)g,
      (__attribute__((address_space(3))) void*)l, 16, 0, 0);
}

// ---------------- feature matching ----------------

// per-pixel channel L2 normalize; block = 16 px x 16 channel-groups, LDS tree reduce.
// blockIdx.y selects feature (f1/f2), blockIdx.z selects batch (strided).
// 16 per-thread values cached in registers across the two passes.
__global__ __launch_bounds__(256) void k_norm2(const float* __restrict__ fA,
                                               const float* __restrict__ fB,
                                               float* __restrict__ fnA,
                                               float* __restrict__ fnB,
                                               float* __restrict__ spixA,
                                               float* __restrict__ spixB,
                                               size_t inStride, size_t outStride,
                                               int sStride){
  const size_t zb = blockIdx.z;
  const float* f  = (blockIdx.y ? fB  : fA) + zb*inStride;
  float* fn       = (blockIdx.y ? fnB : fnA) + zb*outStride;
  float* spix     = (blockIdx.y ? spixB : spixA) + zb*(size_t)sStride;
  __shared__ float red[16][17];
  const int px = threadIdx.x & 15, cg = threadIdx.x >> 4;
  const int pix = blockIdx.x*16 + px;
  float v[16];
  float s = 0.f;
  #pragma unroll
  for (int i=0;i<16;i++){ v[i] = f[(cg*16+i)*HW + pix]; s += v[i]*v[i]; }
  red[cg][px] = s; __syncthreads();
  for (int off=8; off>0; off>>=1){
    if (cg < off) red[cg][px] += red[cg+off][px];
    __syncthreads();
  }
  float n = fmaxf(sqrtf(red[0][px]), 1e-12f);
  float s2 = 0.f;
  #pragma unroll
  for (int i=0;i<16;i++){
    float w = v[i] / n;   // keep fdiv (matches reference rounding)
    fn[(cg*16+i)*HW + pix] = w;
    s2 += w*w;
  }
  __syncthreads();
  red[cg][px] = s2; __syncthreads();
  for (int off=8; off>0; off>>=1){
    if (cg < off) red[cg][px] += red[cg+off][px];
    __syncthreads();
  }
  if (cg == 0) spix[pix] = red[0][px];
}

__global__ __launch_bounds__(256) void k_normpq(const float* __restrict__ s1,
                                                const float* __restrict__ s2,
                                                float* __restrict__ normP,
                                                float* __restrict__ normQ,
                                                int sStride, int nStride){
  int p = blockIdx.x*256 + threadIdx.x;
  if (p >= NPQ) return;
  const size_t zb = blockIdx.z;
  s1 += zb*(size_t)sStride; s2 += zb*(size_t)sStride;
  normP += zb*(size_t)nStride; normQ += zb*(size_t)nStride;
  int py = p/62, px = p - py*62;
  float a=0.f, b=0.f;
  for (int dy=0;dy<3;dy++)
    for (int dx=0;dx<3;dx++){
      int o = (py+dy)*64 + px+dx;
      a += s1[o]; b += s2[o];
    }
  normP[p] = sqrtf(a) + 1e-5f;
  normQ[p] = sqrtf(b) + 1e-5f;
}

// E[m][n] = sum_k A[k][m]*B[k][n]; per-element fmaf chain k=0..255 ascending
// (bit-identical to rounds 3/5). 128m x 256n tile, 8x16 acc/thread, 256 threads.
// BK=16 global_load_lds double-buffered staging, one barrier per K-tile
// (round-6 structure, best measured 377us; round-8 BK=8 experiment refuted the
// LDS-residency theory: 24KB gave same occupancy and +19us from extra barriers).
__global__ __launch_bounds__(256) void k_gemm(const float* __restrict__ A,
                                              const float* __restrict__ B,
                                              float* __restrict__ E,
                                              size_t abStride, size_t eStride){
  __shared__ __align__(16) float As[2][16][128];
  __shared__ __align__(16) float Bs[2][16][256];
  const size_t zb = blockIdx.z;
  A += zb*abStride; B += zb*abStride; E += zb*eStride;
  const int m0 = blockIdx.y*128, n0 = blockIdx.x*256;
  const int tid = threadIdx.x;
  const int ty = tid>>4, tx = tid&15;
  const int wave = tid>>6;              // uniform within wave

  const int arow = tid>>5;
  const int acol = (tid&31)*4;
  const int brow = tid>>6;
  const int bcol = (tid&63)*4;
  const float* Ag = A + (size_t)arow*HW + m0 + acol;
  const float* Bg = B + (size_t)brow*HW + n0 + bcol;

  float acc[8][16];
  #pragma unroll
  for (int i=0;i<8;i++)
    #pragma unroll
    for (int j=0;j<16;j++) acc[i][j]=0.f;

  {
    float* ad = &As[0][0][0] + wave*256;
    float* bd = &Bs[0][0][0] + wave*256;
    gll16(Ag,                    ad);
    gll16(Ag + (size_t)8*HW,     ad + 1024);
    gll16(Bg,                    bd);
    gll16(Bg + (size_t)4*HW,     bd + 1024);
    gll16(Bg + (size_t)8*HW,     bd + 2048);
    gll16(Bg + (size_t)12*HW,    bd + 3072);
  }
  __syncthreads();   // drains vmcnt: tile-0 DMA landed

  for (int t=0;t<16;t++){
    const int cur = t&1;
    if (t < 15){
      const float* An = Ag + (size_t)(t+1)*16*HW;
      const float* Bn = Bg + (size_t)(t+1)*16*HW;
      float* ad = &As[cur^1][0][0] + wave*256;
      float* bd = &Bs[cur^1][0][0] + wave*256;
      gll16(An,                  ad);
      gll16(An + (size_t)8*HW,   ad + 1024);
      gll16(Bn,                  bd);
      gll16(Bn + (size_t)4*HW,   bd + 1024);
      gll16(Bn + (size_t)8*HW,   bd + 2048);
      gll16(Bn + (size_t)12*HW,  bd + 3072);
    }
    #pragma unroll
    for (int k=0;k<16;k++){
      float4 a0 = *(const float4*)&As[cur][k][ty*8];
      float4 a1 = *(const float4*)&As[cur][k][ty*8+4];
      float4 b0 = *(const float4*)&Bs[cur][k][tx*4];
      float4 b1 = *(const float4*)&Bs[cur][k][64+tx*4];
      float4 b2 = *(const float4*)&Bs[cur][k][128+tx*4];
      float4 b3 = *(const float4*)&Bs[cur][k][192+tx*4];
#define GEMM_ROW(i, AV)                                   \
      acc[i][0]  = fmaf(AV, b0.x, acc[i][0]);             \
      acc[i][1]  = fmaf(AV, b0.y, acc[i][1]);             \
      acc[i][2]  = fmaf(AV, b0.z, acc[i][2]);             \
      acc[i][3]  = fmaf(AV, b0.w, acc[i][3]);             \
      acc[i][4]  = fmaf(AV, b1.x, acc[i][4]);             \
      acc[i][5]  = fmaf(AV, b1.y, acc[i][5]);             \
      acc[i][6]  = fmaf(AV, b1.z, acc[i][6]);             \
      acc[i][7]  = fmaf(AV, b1.w, acc[i][7]);             \
      acc[i][8]  = fmaf(AV, b2.x, acc[i][8]);             \
      acc[i][9]  = fmaf(AV, b2.y, acc[i][9]);             \
      acc[i][10] = fmaf(AV, b2.z, acc[i][10]);            \
      acc[i][11] = fmaf(AV, b2.w, acc[i][11]);            \
      acc[i][12] = fmaf(AV, b3.x, acc[i][12]);            \
      acc[i][13] = fmaf(AV, b3.y, acc[i][13]);            \
      acc[i][14] = fmaf(AV, b3.z, acc[i][14]);            \
      acc[i][15] = fmaf(AV, b3.w, acc[i][15]);
      GEMM_ROW(0, a0.x)
      GEMM_ROW(1, a0.y)
      GEMM_ROW(2, a0.z)
      GEMM_ROW(3, a0.w)
      GEMM_ROW(4, a1.x)
      GEMM_ROW(5, a1.y)
      GEMM_ROW(6, a1.z)
      GEMM_ROW(7, a1.w)
#undef GEMM_ROW
    }
    __syncthreads();  // drains vmcnt (tile t+1 DMA) + all waves done reading buf cur
  }

  #pragma unroll
  for (int i=0;i<8;i++){
    float* rowp = E + (size_t)(m0+ty*8+i)*HW + n0;
    *(float4*)(rowp + tx*4)       = make_float4(acc[i][0], acc[i][1], acc[i][2], acc[i][3]);
    *(float4*)(rowp + 64 + tx*4)  = make_float4(acc[i][4], acc[i][5], acc[i][6], acc[i][7]);
    *(float4*)(rowp + 128 + tx*4) = make_float4(acc[i][8], acc[i][9], acc[i][10], acc[i][11]);
    *(float4*)(rowp + 192 + tx*4) = make_float4(acc[i][12], acc[i][13], acc[i][14], acc[i][15]);
  }
}

// per patch P: max/argmax over Q (round-5 arithmetic; blockIdx.y = batch).
// Bijective XCD swizzle of the patch index for per-XCD L2 reuse of E row-bands.
// Round 14: final reduction via wave shfl_xor butterfly (no barriers) + 4-partial
// LDS finish. (max, min-idx) reduction has a unique fixed point independent of
// order -> identical (val,idx) to the old 8-step tree.
__global__ __launch_bounds__(256) void k_reduce(const float* __restrict__ E,
                                                const float* __restrict__ normP,
                                                const float* __restrict__ normQ,
                                                float* __restrict__ maxval,
                                                int* __restrict__ maxidx,
                                                size_t eStride, int nStride){
  // m204 bijective swizzle: NPQ = 3844 = 8*480 + 4
  const int orig = blockIdx.x;
  const int xcd = orig & 7, ii = orig >> 3;
  const int qc = NPQ >> 3, rc = NPQ & 7;   // 480, 4
  const int p = (xcd < rc) ? xcd*(qc+1) + ii : rc*(qc+1) + (xcd-rc)*qc + ii;

  const int bz = blockIdx.y;
  E += (size_t)bz*eStride;
  normP += (size_t)bz*(size_t)nStride;
  normQ += (size_t)bz*(size_t)nStride;
  const int py = p/62, px = p - py*62;
  const int t = threadIdx.x;
  float best = -3.0e38f; int bq = 1<<30;

  if (t < 248){
    const int qy = t >> 2, g = t & 3;
    const int qx0 = g*16;
    const int cnt = (g==3) ? 14 : 16;
    float s[16];
    #pragma unroll
    for (int j=0;j<16;j++) s[j]=0.f;
    #pragma unroll
    for (int dy=0;dy<3;dy++){
      const int cbase = (qy+dy)*64 + qx0;
      #pragma unroll
      for (int dx=0;dx<3;dx++){
        const float* row = E + (size_t)((py+dy)*64 + px+dx)*HW + cbase;
        float4 w0 = *(const float4*)(row);
        float4 w1 = *(const float4*)(row+4);
        float4 w2 = *(const float4*)(row+8);
        float4 w3 = *(const float4*)(row+12);
        float4 w4 = (g<3) ? *(const float4*)(row+16) : make_float4(0.f,0.f,0.f,0.f);
        float w[20] = {w0.x,w0.y,w0.z,w0.w, w1.x,w1.y,w1.z,w1.w,
                       w2.x,w2.y,w2.z,w2.w, w3.x,w3.y,w3.z,w3.w,
                       w4.x,w4.y,w4.z,w4.w};
        #pragma unroll
        for (int j=0;j<16;j++) s[j] += w[dx+j];
      }
    }
    const int qbase = qy*62 + qx0;
    for (int j=0;j<cnt;j++){
      float v = s[j] / normQ[qbase + j];
      if (v > best){ best = v; bq = qbase + j; }
    }
  }

  // wave butterfly (64 lanes, 6 steps, no barriers)
  #pragma unroll
  for (int off=32; off>0; off>>=1){
    float ov = __shfl_xor(best, off);
    int   oi = __shfl_xor(bq, off);
    if (ov > best || (ov == best && oi < bq)){ best = ov; bq = oi; }
  }
  __shared__ float wv[4];
  __shared__ int   wi[4];
  if ((t & 63) == 0){ wv[t>>6] = best; wi[t>>6] = bq; }
  __syncthreads();
  if (t == 0){
    float v = wv[0]; int bi = wi[0];
    #pragma unroll
    for (int w2=1; w2<4; w2++){
      float ov = wv[w2]; int oi = wi[w2];
      if (ov > v || (ov == v && oi < bi)){ v = ov; bi = oi; }
    }
    maxval[bz*NPQ + p] = v / normP[p];
    maxidx[bz*NPQ + p] = bi;
  }
}

// ---------------- flow / sim outputs ----------------

__global__ __launch_bounds__(256) void k_flow3(const int* __restrict__ maxidx,
                                               const float* __restrict__ maxval,
                                               float* __restrict__ flow3ws,
                                               float* __restrict__ sim3ws,
                                               float* __restrict__ oflow,
                                               float* __restrict__ osim){
  int idx = blockIdx.x*256 + threadIdx.x;
  if (idx >= 4*HW) return;
  int b = idx >> 12, r = idx & 4095;
  int y = r >> 6, x = r & 63;
  float fx = 0.f, fy = 0.f;
  if (y < 62 && x < 62){
    int mi = maxidx[b*NPQ + y*62 + x];
    int qy = mi/62, qx = mi - qy*62;
    fx = (float)(qx - x);
    fy = (float)(qy - y);
  }
  flow3ws[idx*2] = fx; flow3ws[idx*2+1] = fy;
  oflow[idx*2] = fx; oflow[idx*2+1] = fy;
  float sv = 0.f;
  if (y >= 1 && y <= 62 && x >= 1 && x <= 62)
    sv = maxval[b*NPQ + (y-1)*62 + (x-1)];
  sim3ws[idx] = sv;
  osim[idx] = sv;
}

// Round 14: all remaining flow/sim/offset outputs in ONE flat-index launch.
// Region bodies are verbatim copies of the old k_off3/k_offS/k_flowS math
// (integer indexing + exact x2/x4 scaling) -> bit-identical outputs.
// slots: off3 147456(f2) | off2 589824(f2) | off1 2359296(f2)
//      | flow2 65536(f2) | flow1 262144(f2) | sim2 65536(f) | sim1 262144(f)
// total 3751936 = 14656 blocks x 256
__global__ __launch_bounds__(256) void k_outs(const float* __restrict__ fl3,
                                              const float* __restrict__ sm3,
                                              float* __restrict__ out){
  int idx = blockIdx.x*256 + threadIdx.x;

  if (idx < 147456){                       // off3
    int b = idx / 36864;
    int rem = idx - b*36864;
    int k = rem >> 12;
    int r = rem & 4095;
    int y = r >> 6, x = r & 63;
    int i = k/3, j = k - i*3;
    float fx = 0.f, fy = 0.f;
    if (y >= i && x >= j){
      int s = (b*HW + (y-i)*64 + (x-j))*2;
      fx = fl3[s]; fy = fl3[s+1];
    }
    out[O_OFF3 + (size_t)idx*2] = fx; out[O_OFF3 + (size_t)idx*2+1] = fy;
    return;
  }
  idx -= 147456;
  if (idx < 589824){                       // off2 (S=2, N=128)
    int b = idx / 147456;
    int rem = idx - b*147456;
    int k = rem / 16384;
    int r = rem - k*16384;
    int y = r >> 7, x = r & 127;
    int i = k/3, j = k - i*3;
    float fx = 0.f, fy = 0.f;
    int sy = y - 2*i, sx = x - 2*j;
    if (sy >= 0 && sx >= 0){
      int s = (b*HW + (sy/2)*64 + (sx/2))*2;
      fx = fl3[s] * 2.f; fy = fl3[s+1] * 2.f;
    }
    out[O_OFF2 + (size_t)idx*2] = fx; out[O_OFF2 + (size_t)idx*2+1] = fy;
    return;
  }
  idx -= 589824;
  if (idx < 2359296){                      // off1 (S=4, N=256)
    int b = idx / 589824;
    int rem = idx - b*589824;
    int k = rem / 65536;
    int r = rem - k*65536;
    int y = r >> 8, x = r & 255;
    int i = k/3, j = k - i*3;
    float fx = 0.f, fy = 0.f;
    int sy = y - 4*i, sx = x - 4*j;
    if (sy >= 0 && sx >= 0){
      int s = (b*HW + (sy/4)*64 + (sx/4))*2;
      fx = fl3[s] * 4.f; fy = fl3[s+1] * 4.f;
    }
    out[O_OFF1 + (size_t)idx*2] = fx; out[O_OFF1 + (size_t)idx*2+1] = fy;
    return;
  }
  idx -= 2359296;
  if (idx < 65536){                        // flow2 (S=2, N=128)
    int b = idx / 16384;
    int r = idx - b*16384;
    int y = r >> 7, x = r & 127;
    int s = b*HW + (y/2)*64 + (x/2);
    out[O_FLOW2 + (size_t)idx*2]   = fl3[s*2]   * 2.f;
    out[O_FLOW2 + (size_t)idx*2+1] = fl3[s*2+1] * 2.f;
    return;
  }
  idx -= 65536;
  if (idx < 262144){                       // flow1 (S=4, N=256)
    int b = idx / 65536;
    int r = idx - b*65536;
    int y = r >> 8, x = r & 255;
    int s = b*HW + (y/4)*64 + (x/4);
    out[O_FLOW1 + (size_t)idx*2]   = fl3[s*2]   * 4.f;
    out[O_FLOW1 + (size_t)idx*2+1] = fl3[s*2+1] * 4.f;
    return;
  }
  idx -= 262144;
  if (idx < 65536){                        // sim2 (S=2, N=128)
    int b = idx / 16384;
    int r = idx - b*16384;
    int y = r >> 7, x = r & 127;
    int s = b*HW + (y/2)*64 + (x/2);
    out[O_SIM2 + (size_t)idx] = sm3[s];
    return;
  }
  idx -= 65536;
  if (idx < 262144){                       // sim1 (S=4, N=256)
    int b = idx / 65536;
    int r = idx - b*65536;
    int y = r >> 8, x = r & 255;
    int s = b*HW + (y/4)*64 + (x/4);
    out[O_SIM1 + (size_t)idx] = sm3[s];
  }
}

// ---------------- VGG ----------------

// weight transform: fp32 OIHW -> bf16 [tap][oc][ci]
__global__ __launch_bounds__(256) void k_wt(const float* __restrict__ w,
                                            ushort* __restrict__ wt,
                                            int Cout, int Cin){
  int idx = blockIdx.x*256 + threadIdx.x;
  int tot = Cout*Cin*9;
  if (idx >= tot) return;
  int o = idx / (Cin*9);
  int rem = idx - o*(Cin*9);
  int i = rem / 9;
  int tap = rem - i*9;
  wt[((size_t)tap*Cout + o)*Cin + i] = f2bu(w[idx]);
}

// conv1_1: direct fp32, Cin=3, H=W=256, fused imagenet normalize; batched via z
// (z: b = z>>3, oc-group = z&7). Writes fp32 CHW (d_out) + bf16 HWC (next stage).
__global__ __launch_bounds__(256) void k_conv1(const float* __restrict__ img,
                                               const float* __restrict__ w,
                                               const float* __restrict__ bias,
                                               float* __restrict__ outf,
                                               ushort* __restrict__ outb){
  __shared__ float sIn[3][18][20];
  __shared__ float sW[8][3][9];
  const int tx = threadIdx.x & 15, ty = threadIdx.x >> 4;
  const int x0 = blockIdx.x*16, y0 = blockIdx.y*16;
  const int b = blockIdx.z >> 3;
  const int oc0 = (blockIdx.z & 7)*8;
  const float MEAN[3] = {0.485f,0.456f,0.406f};
  const float STDV[3] = {0.229f,0.224f,0.225f};
  const float* in = img + (size_t)b*3*65536;
  for (int i = threadIdx.x; i < 3*324; i += 256){
    int ci = i / 324;
    int rr = i - ci*324;
    int iy = rr / 18, ix = rr - iy*18;
    int gy = y0 + iy - 1, gx = x0 + ix - 1;
    float v = 0.f;
    if (gy >= 0 && gy < 256 && gx >= 0 && gx < 256)
      v = (in[ci*65536 + gy*256 + gx] - MEAN[ci]) / STDV[ci];
    sIn[ci][iy][ix] = v;
  }
  if (threadIdx.x < 216){
    int o = threadIdx.x / 27;
    int rr = threadIdx.x - o*27;
    int ci = rr / 9, t = rr - ci*9;
    sW[o][ci][t] = w[((oc0+o)*3 + ci)*9 + t];
  }
  __syncthreads();
  float acc[8] = {0.f,0.f,0.f,0.f,0.f,0.f,0.f,0.f};
  for (int ci=0; ci<3; ci++){
    #pragma unroll
    for (int ky=0;ky<3;ky++){
      #pragma unroll
      for (int kx=0;kx<3;kx++){
        float v = sIn[ci][ty+ky][tx+kx];
        #pragma unroll
        for (int o=0;o<8;o++)
          acc[o] = fmaf(v, sW[o][ci][ky*3+kx], acc[o]);
      }
    }
  }
  #pragma unroll
  for (int o=0;o<8;o++){
    float r = fmaxf(acc[o] + bias[oc0+o], 0.f);
    outf[(size_t)b*4194304 + (size_t)(oc0+o)*65536 + (size_t)(y0+ty)*256 + (x0+tx)] = r;
    outb[(size_t)b*4194304 + ((size_t)(y0+ty)*256 + (x0+tx))*64 + (oc0+o)] = f2bu(r);
  }
}

// MFMA implicit-GEMM 3x3 SAME conv, bf16 in / fp32 acc; batched via z
// (z = b*zDiv + oc-tile; per-batch pointer strides in elements).
// A-fragments (weights) read directly from global (L2-hot, shared by all blocks);
// LDS holds only sX; one barrier per block.
__global__ __launch_bounds__(256) void k_conv_mfma(const ushort* __restrict__ X,
                                                   const ushort* __restrict__ Wt,
                                                   const float* __restrict__ bias,
                                                   ushort* __restrict__ outHWC,
                                                   float* __restrict__ outCHW,
                                                   int Cin, int Cout, int H, int W,
                                                   int zDiv, size_t xStride,
                                                   size_t hwcStride, size_t chwStride){
  extern __shared__ ushort smem[];
  const int CS = Cin + 8;
  ushort* sX = smem;                      // [10][18][CS]
  const int tid = threadIdx.x;
  const int wave = tid >> 6, lane = tid & 63;
  const int quad = lane >> 4, l16 = lane & 15;
  const int bz = blockIdx.z / zDiv;
  const int zo = blockIdx.z - bz*zDiv;
  const int x0 = blockIdx.x * 16, y0 = blockIdx.y * 8, oc0 = zo * 64;
  X += (size_t)bz * xStride;
  if (outHWC) outHWC += (size_t)bz * hwcStride;
  if (outCHW) outCHW += (size_t)bz * chwStride;
  const int nci8 = Cin >> 3;
  const int c8s = (Cin == 128) ? 4 : 3;
  const int c8m = nci8 - 1;

  for (int i = tid; i < 180*nci8; i += 256){
    int c8 = i & c8m;
    int rest = i >> c8s;
    int px = rest % 18;
    int row = rest / 18;
    int gy = y0 - 1 + row, gx = x0 - 1 + px;
    uint4 v = make_uint4(0u,0u,0u,0u);
    if (gy >= 0 && gy < H && gx >= 0 && gx < W)
      v = *(const uint4*)(X + ((size_t)gy*W + gx)*Cin + c8*8);
    *(uint4*)(sX + (row*18 + px)*CS + c8*8) = v;
  }
  __syncthreads();

  f32x4 acc[2][4];
  #pragma unroll
  for (int m=0;m<2;m++)
    #pragma unroll
    for (int r=0;r<4;r++) acc[m][r] = (f32x4){0.f,0.f,0.f,0.f};

  const int my = (wave>>1)*4;
  const int mo = (wave&1)*32;

  for (int tap = 0; tap < 9; tap++){
    int dy = tap/3 - 1, dx = tap - (tap/3)*3 - 1;
    const ushort* wsrc = Wt + ((size_t)tap*Cout + oc0)*Cin;
    for (int k0 = 0; k0 < Cin; k0 += 32){
      bf16x8 A0 = *(const bf16x8*)(wsrc + (mo + l16)*Cin + k0 + quad*8);
      bf16x8 A1 = *(const bf16x8*)(wsrc + (mo + 16 + l16)*Cin + k0 + quad*8);
      #pragma unroll
      for (int r = 0; r < 4; r++){
        bf16x8 B = *(const bf16x8*)(sX + ((1 + my + r + dy)*18 + (1 + l16 + dx))*CS + k0 + quad*8);
        acc[0][r] = __builtin_amdgcn_mfma_f32_16x16x32_bf16(A0, B, acc[0][r], 0, 0, 0);
        acc[1][r] = __builtin_amdgcn_mfma_f32_16x16x32_bf16(A1, B, acc[1][r], 0, 0, 0);
      }
    }
  }

  const int x = x0 + l16;
  #pragma unroll
  for (int m = 0; m < 2; m++){
    int ocb = oc0 + mo + m*16 + quad*4;
    float4 bv = *(const float4*)(bias + ocb);
    #pragma unroll
    for (int r = 0; r < 4; r++){
      int y = y0 + my + r;
      float v0 = fmaxf(acc[m][r][0] + bv.x, 0.f);
      float v1 = fmaxf(acc[m][r][1] + bv.y, 0.f);
      float v2 = fmaxf(acc[m][r][2] + bv.z, 0.f);
      float v3 = fmaxf(acc[m][r][3] + bv.w, 0.f);
      if (outHWC){
        uint lo = (uint)f2bu(v0) | ((uint)f2bu(v1) << 16);
        uint hi = (uint)f2bu(v2) | ((uint)f2bu(v3) << 16);
        // GLOBAL oc index (round-4 bug: localizing collided z-tiles)
        uint2* dst = (uint2*)(outHWC + ((size_t)y*W + x)*Cout + ocb);
        *dst = make_uint2(lo, hi);
      }
      if (outCHW){
        size_t base = (size_t)ocb*H*W + (size_t)y*W + x;
        outCHW[base]                 = v0;
        outCHW[base +   (size_t)H*W] = v1;
        outCHW[base + 2*(size_t)H*W] = v2;
        outCHW[base + 3*(size_t)H*W] = v3;
      }
    }
  }
}

// 2x2 max-pool on HWC bf16 (post-relu, non-negative -> u16 compare); batched via z
__global__ __launch_bounds__(256) void k_pool_h(const ushort* __restrict__ in,
                                                ushort* __restrict__ out,
                                                int C, int Wo, int s,
                                                size_t inStride, size_t outStride){
  in  += (size_t)blockIdx.z * inStride;
  out += (size_t)blockIdx.z * outStride;
  int idx = blockIdx.x*256 + threadIdx.x;
  int nc8 = C >> 3;
  if (idx >= Wo*nc8) return;
  int x = idx >> s;
  int c8 = idx & (nc8 - 1);
  int y = blockIdx.y;
  int Wi = 2*Wo;
  const ushort* p = in + ((size_t)(2*y)*Wi + 2*x)*C + c8*8;
  uint4 a = *(const uint4*)p;
  uint4 b = *(const uint4*)(p + C);
  uint4 c = *(const uint4*)(p + (size_t)Wi*C);
  uint4 d = *(const uint4*)(p + (size_t)Wi*C + C);
  uint4 m;
  m.x = umax2x16(umax2x16(a.x,b.x), umax2x16(c.x,d.x));
  m.y = umax2x16(umax2x16(a.y,b.y), umax2x16(c.y,d.y));
  m.z = umax2x16(umax2x16(a.z,b.z), umax2x16(c.z,d.z));
  m.w = umax2x16(umax2x16(a.w,b.w), umax2x16(c.w,d.w));
  *(uint4*)(out + ((size_t)y*Wo + x)*C + c8*8) = m;
}

// ---------------- launch ----------------

extern "C" void kernel_launch(void* const* d_in, const int* in_sizes, int n_in,
                              void* d_out, int out_size, void* d_ws, size_t ws_size,
                              hipStream_t stream){
  const float* f1  = (const float*)d_in[0];
  const float* f2  = (const float*)d_in[1];
  const float* img = (const float*)d_in[2];
  const float* w11 = (const float*)d_in[3];  const float* b11 = (const float*)d_in[4];
  const float* w12 = (const float*)d_in[5];  const float* b12 = (const float*)d_in[6];
  const float* w21 = (const float*)d_in[7];  const float* b21 = (const float*)d_in[8];
  const float* w22 = (const float*)d_in[9];  const float* b22 = (const float*)d_in[10];
  const float* w31 = (const float*)d_in[11]; const float* b31 = (const float*)d_in[12];
  float* out = (float*)d_out;

  float* F = (float*)d_ws;
  float* E = F;                         // batch-0 E (64 MB); VGG reuses this region

  // VGG weight buffers (dead region after matching in both layouts)
  ushort* wt1  = (ushort*)(F + 16777216);
  ushort* wt2a = (ushort*)(F + 16795648);
  ushort* wt2b = (ushort*)(F + 16832512);
  ushort* wt3  = (ushort*)(F + 16906240);

  // VGG activations alias the E region (64 MB), all 4 batches concurrently.
  ushort* EU  = (ushort*)E;
  ushort* t1a = EU;                 // 4 x 4,194,304
  ushort* t2a = EU + 16777216;      // 4 x 4,194,304
  ushort* p1a = EU;                 // 4 x 1,048,576  (t1 dead)
  ushort* t3a = EU + 4194304;       // 4 x 2,097,152
  ushort* t4a = EU + 16777216;      // 4 x 2,097,152  (t2 dead)
  ushort* p2a = EU;                 // 4 x   524,288  (p1 dead)

  // Big-workspace layout: 4x E (256 MB) + staging past it. ~302.6 MB total.
  const bool big = ws_size >= 302600000ull;

  float *mval, *fl3, *sm3; int* midx;

  if (big){
    float* f1n = F + 67108864;   // 4 x 1,048,576
    float* f2n = F + 71303168;   // 4 x 1,048,576
    float* s1  = F + 75497472;   // 4 x 4096
    float* s2  = F + 75513856;
    float* nP  = F + 75530240;   // 4 x 4096
    float* nQ  = F + 75546624;
    mval = F + 75563008;         // 4 x 4096
    midx = (int*)(F + 75579392);
    fl3  = F + 75595776;         // 4 x 4096 x 2
    sm3  = F + 75628544;         // 4 x 4096

    // fully batched matching: one launch per stage, grid.z = batch
    k_norm2<<<dim3(256,2,4),256,0,stream>>>(f1, f2, f1n, f2n, s1, s2,
                                            (size_t)256*HW, 1048576, 4096);
    k_normpq<<<dim3(16,1,4),256,0,stream>>>(s1, s2, nP, nQ, 4096, 4096);
    k_gemm<<<dim3(16,32,4),256,0,stream>>>(f1n, f2n, E, 1048576, 16777216);
    k_reduce<<<dim3(NPQ,4),256,0,stream>>>(E, nP, nQ, mval, midx, 16777216, 4096);
  } else {
    // fallback: serial layout (E reused per batch)
    float* f1n  = F + 16777216;
    float* f2n  = F + 17825792;
    float* s1   = F + 18874368;
    float* s2   = F + 18878464;
    float* nP   = F + 18882560;
    float* nQ   = F + 18886656;
    mval = F + 18890752;
    midx = (int*)(F + 18907136);
    fl3  = F + 18923520;
    sm3  = F + 18956288;

    for (int b=0;b<4;b++){
      const float* f1b  = f1 + (size_t)b*256*HW;
      const float* f2b2 = f2 + (size_t)b*256*HW;
      k_norm2<<<dim3(256,2,1),256,0,stream>>>(f1b, f2b2, f1n, f2n, s1, s2, 0, 0, 0);
      k_normpq<<<dim3(16,1,1),256,0,stream>>>(s1, s2, nP, nQ, 0, 0);
      k_gemm<<<dim3(16,32,1),256,0,stream>>>(f1n, f2n, E, 0, 0);
      k_reduce<<<dim3(NPQ,1),256,0,stream>>>(E, nP, nQ, mval + b*NPQ, midx + b*NPQ, 0, 0);
    }
  }

  k_flow3<<<64,256,0,stream>>>(midx, mval, fl3, sm3, out+O_FLOW3, out+O_SIM3);
  k_outs<<<14656,256,0,stream>>>(fl3, sm3, out);

  k_wt<<<144,256,0,stream>>>(w12, wt1, 64, 64);
  k_wt<<<288,256,0,stream>>>(w21, wt2a, 128, 64);
  k_wt<<<576,256,0,stream>>>(w22, wt2b, 128, 128);
  k_wt<<<1152,256,0,stream>>>(w31, wt3, 256, 128);

  const int smem64  = 180*72*2;    // sX only
  const int smem128 = 180*136*2;

  // batched VGG (grid.z carries batch)
  k_conv1<<<dim3(16,16,32),256,0,stream>>>(img, w11, b11, out + O_R1, t1a);
  k_conv_mfma<<<dim3(16,32,4),256,smem64,stream>>>(t1a, wt1, b12, t2a, nullptr,
      64, 64, 256, 256, 1, 4194304, 4194304, 0);
  k_pool_h<<<dim3(4,128,4),256,0,stream>>>(t2a, p1a, 64, 128, 3, 4194304, 1048576);
  k_conv_mfma<<<dim3(8,16,8),256,smem64,stream>>>(p1a, wt2a, b21, t3a, out + O_R2,
      64, 128, 128, 128, 2, 1048576, 2097152, 2097152);
  k_conv_mfma<<<dim3(8,16,8),256,smem128,stream>>>(t3a, wt2b, b22, t4a, nullptr,
      128, 128, 128, 128, 2, 2097152, 2097152, 0);
  k_pool_h<<<dim3(4,64,4),256,0,stream>>>(t4a, p2a, 128, 64, 4, 2097152, 524288);
  k_conv_mfma<<<dim3(4,8,16),256,smem128,stream>>>(p2a, wt3, b31, nullptr, out + O_R3,
      128, 256, 64, 64, 4, 524288, 0, 1048576);
}